// Round 5
// baseline (183.635 us; speedup 1.0000x reference)
//
#include <hip/hip_runtime.h>
#include <math.h>
#include <stdint.h>

#define D_MODEL 2048
#define NEXP    64
#define TOKENS  32768
#define BM      128
#define BK      32
#define NT      512
#define NCHUNK  (D_MODEL / BK)   // 64
#define BUFSZ   24576            // 16KB x-tile + 8KB W-tile
#define TIE_THR 1e-3f            // 3-term split logit err rms ~1e-5; wide margin
#define LSTRIDE 66

typedef __attribute__((ext_vector_type(8))) short short8;  // MFMA A/B frag
typedef __attribute__((ext_vector_type(4))) float f32x4;   // MFMA C/D frag
typedef __attribute__((ext_vector_type(4))) int   i32x4;

typedef __attribute__((address_space(3))) uint32_t       lds_u32_t;
typedef const __attribute__((address_space(1))) uint32_t gbl_u32_t;

// hi = fp32 top-16 (RTZ bf16); lo = bf16(f - hi). (hi+lo) error <= 2^-16 rel.
__device__ __forceinline__ void split2(float f0, float f1, uint32_t& hw, uint32_t& lw)
{
    const uint32_t u0 = __float_as_uint(f0), u1 = __float_as_uint(f1);
    const uint32_t a0 = u0 & 0xffff0000u, a1 = u1 & 0xffff0000u;
    hw = a1 | (u0 >> 16);
    const float l0 = f0 - __uint_as_float(a0);
    const float l1 = f1 - __uint_as_float(a1);
    lw = (__float_as_uint(l1) & 0xffff0000u) | (__float_as_uint(l0) >> 16);
}

// Read one fp32 k-octet (two swizzled b128 quads) -> hi/lo bf16 fragments.
__device__ __forceinline__ void ldsplit(const char* p0, const char* p1,
                                        short8& h8, short8& l8)
{
    const float4 qa = *(const float4*)p0;   // k+0..3
    const float4 qb = *(const float4*)p1;   // k+4..7
    i32x4 hv, lv;
    uint32_t hw, lw;
    split2(qa.x, qa.y, hw, lw); hv[0] = (int)hw; lv[0] = (int)lw;
    split2(qa.z, qa.w, hw, lw); hv[1] = (int)hw; lv[1] = (int)lw;
    split2(qb.x, qb.y, hw, lw); hv[2] = (int)hw; lv[2] = (int)lw;
    split2(qb.z, qb.w, hw, lw); hv[3] = (int)hw; lv[3] = (int)lw;
    h8 = *(short8*)&hv;
    l8 = *(short8*)&lv;
}

// counted vmcnt (T4): keep later chunks' loads in flight across the barrier
#define WAITVM(N) asm volatile("s_waitcnt vmcnt(" #N ")" ::: "memory")

// Stage chunk c into buffer b: 3 x 1KB global_load_lds per wave.
// Source col pre-swizzled (quad ^ (row&7)); LDS image linear (rule #21).
#define STAGE(c, b)                                                              \
    do {                                                                         \
        char* bb_ = smem + (b) * BUFSZ;                                          \
        __builtin_amdgcn_global_load_lds((gbl_u32_t*)(xsrc0 + (size_t)(c) * BK), \
            (lds_u32_t*)(bb_ + 2048 * wave), 16, 0, 0);                          \
        __builtin_amdgcn_global_load_lds((gbl_u32_t*)(xsrc1 + (size_t)(c) * BK), \
            (lds_u32_t*)(bb_ + 2048 * wave + 1024), 16, 0, 0);                   \
        __builtin_amdgcn_global_load_lds((gbl_u32_t*)(wsrc0 + (size_t)(c) * BK), \
            (lds_u32_t*)(bb_ + 16384 + 1024 * wave), 16, 0, 0);                  \
    } while (0)

// One K=32 step: 4 ldsplits + 12 MFMA (3-term split product).
#define COMPUTE(b)                                                               \
    do {                                                                         \
        const char* xb_ = smem + (b) * BUFSZ;                                    \
        const char* wb_ = xb_ + 16384;                                           \
        short8 ah_[2], al_[2], bh_[2], bl_[2];                                   \
        _Pragma("unroll")                                                        \
        for (int mi = 0; mi < 2; ++mi)                                           \
            ldsplit(xb_ + oA[mi], xb_ + (oA[mi] ^ 16), ah_[mi], al_[mi]);        \
        _Pragma("unroll")                                                        \
        for (int ni = 0; ni < 2; ++ni)                                           \
            ldsplit(wb_ + oB[ni], wb_ + (oB[ni] ^ 16), bh_[ni], bl_[ni]);        \
        _Pragma("unroll")                                                        \
        for (int mi = 0; mi < 2; ++mi)                                           \
            _Pragma("unroll")                                                    \
            for (int ni = 0; ni < 2; ++ni) {                                     \
                acc[mi][ni] = __builtin_amdgcn_mfma_f32_16x16x32_bf16(ah_[mi], bh_[ni], acc[mi][ni], 0, 0, 0); \
                acc[mi][ni] = __builtin_amdgcn_mfma_f32_16x16x32_bf16(al_[mi], bh_[ni], acc[mi][ni], 0, 0, 0); \
                acc[mi][ni] = __builtin_amdgcn_mfma_f32_16x16x32_bf16(ah_[mi], bl_[ni], acc[mi][ni], 0, 0, 0); \
            }                                                                    \
    } while (0)

__global__ __launch_bounds__(NT, 2)
void router_kernel(const float* __restrict__ x, const float* __restrict__ W,
                   float* __restrict__ out)
{
    __shared__ char smem[4 * BUFSZ];    // 96 KB: 4 pipeline buffers
    __shared__ int  flaglist[BM];
    __shared__ int  nflag;

    const int tid  = threadIdx.x;
    const int lane = tid & 63;
    const int wave = tid >> 6;          // 0..7
    const int row0 = blockIdx.x * BM;

    // ---- staging sources (pre-swizzled) ----
    // x packets: wave rows 16w+8g+(lane>>3); W packet: rows 8w+(lane>>3).
    const int srow = lane >> 3;                 // row-within-packet = row&7
    const int scol = 4 * ((lane & 7) ^ srow);   // pre-swizzled col
    const float* xsrc0 = x + (size_t)(row0 + 16 * wave + srow) * D_MODEL + scol;
    const float* xsrc1 = x + (size_t)(row0 + 16 * wave + 8 + srow) * D_MODEL + scol;
    const float* wsrc0 = W + (size_t)(8 * wave + srow) * D_MODEL + scol;

    // ---- fragment geometry: wave covers 32 tokens x 32 experts ----
    const int fr = lane & 15;
    const int h  = lane >> 4;                   // k-octet group
    const int m0 = 32 * (wave >> 1);            // token base
    const int n0 = 32 * (wave & 1);             // expert base
    int oA[2], oB[2];
#pragma unroll
    for (int i = 0; i < 2; ++i) {
        oA[i] = (m0 + 16 * i + fr) * 128 + 16 * ((2 * h) ^ (fr & 7));
        oB[i] = (n0 + 16 * i + fr) * 128 + 16 * ((2 * h) ^ (fr & 7));
    }

    f32x4 acc[2][2] = {};

    STAGE(0, 0);
    STAGE(1, 1);
    STAGE(2, 2);

    for (int c = 0; c < NCHUNK - 3; ++c) {
        WAITVM(6);                                // chunk c landed; c+1,c+2 in flight
        __builtin_amdgcn_s_barrier();
        __builtin_amdgcn_sched_barrier(0);        // no ds_read hoist above wait (rule #18)
        STAGE(c + 3, (c + 3) & 3);
        COMPUTE(c & 3);
    }
    WAITVM(6); __builtin_amdgcn_s_barrier(); __builtin_amdgcn_sched_barrier(0);
    COMPUTE((NCHUNK - 3) & 3);
    WAITVM(3); __builtin_amdgcn_s_barrier(); __builtin_amdgcn_sched_barrier(0);
    COMPUTE((NCHUNK - 2) & 3);
    WAITVM(0); __builtin_amdgcn_s_barrier(); __builtin_amdgcn_sched_barrier(0);
    COMPUTE((NCHUNK - 1) & 3);
    __syncthreads();

    // ---- epilogue: logits [128][66] into dead buffer region ----
    float* logits = (float*)smem;
#pragma unroll
    for (int mi = 0; mi < 2; ++mi)
#pragma unroll
        for (int ni = 0; ni < 2; ++ni)
#pragma unroll
            for (int r = 0; r < 4; ++r)
                logits[(m0 + 16 * mi + 4 * h + r) * LSTRIDE + n0 + 16 * ni + fr] =
                    acc[mi][ni][r];
    if (tid == 0) nflag = 0;
    __syncthreads();

    // ---- top-3 scan, flag near-ties for exact recompute ----
    float m1 = -INFINITY, m2 = -INFINITY, m3 = -INFINITY;
    int   i1 = 0, i2 = 0;
    bool  tie = false;
    if (tid < BM) {
#pragma unroll 8
        for (int e = 0; e < NEXP; ++e) {
            const float v = logits[tid * LSTRIDE + e];
            if (v > m1)      { m3 = m2; m2 = m1; i2 = i1; m1 = v; i1 = e; }
            else if (v > m2) { m3 = m2; m2 = v; i2 = e; }
            else if (v > m3) { m3 = v; }
        }
        tie = (m1 - m2 < TIE_THR) || (m2 - m3 < TIE_THR);
        if (tie) { const int p = atomicAdd(&nflag, 1); flaglist[p] = tid; }
    }
    __syncthreads();

    // ---- exact fp32 cleanup for flagged tokens (~1 per block) ----
    const int nf = nflag;
    float* partial = (float*)(smem + 65536);   // [8][64], dead region
    for (int f = 0; f < nf; ++f) {
        const int t = flaglist[f];
        const float* xr   = x + (size_t)(row0 + t) * D_MODEL + 256 * wave;
        const float* wrow = W + (size_t)lane * D_MODEL + 256 * wave;
        float ps = 0.f;
        for (int k = 0; k < 256; k += 4) {
            const float4 xv = *(const float4*)(xr + k);
            const float4 wv = *(const float4*)(wrow + k);
            ps = fmaf(xv.x, wv.x, ps); ps = fmaf(xv.y, wv.y, ps);
            ps = fmaf(xv.z, wv.z, ps); ps = fmaf(xv.w, wv.w, ps);
        }
        partial[wave * 64 + lane] = ps;
        __syncthreads();
        if (tid < NEXP) {
            float s = 0.f;
#pragma unroll
            for (int wv = 0; wv < 8; ++wv) s += partial[wv * 64 + tid];
            logits[t * LSTRIDE + tid] = s;
        }
        __syncthreads();
    }

    if (tid < BM) {
        if (tie) {   // rescan exact row
            m1 = -INFINITY; m2 = -INFINITY; i1 = 0; i2 = 0;
#pragma unroll 8
            for (int e = 0; e < NEXP; ++e) {
                const float v = logits[tid * LSTRIDE + e];
                if (v > m1)      { m2 = m1; i2 = i1; m1 = v; i1 = e; }
                else if (v > m2) { m2 = v; i2 = e; }
            }
        }
        const float ex = expf(m2 - m1);      // renormalized top-2 softmax
        const float g1 = 1.0f / (1.0f + ex);
        const float g2 = ex * g1;
        const int row = row0 + tid;
        out[(size_t)row * 2 + 0] = g1;
        out[(size_t)row * 2 + 1] = g2;
        out[(size_t)TOKENS * 2 + (size_t)row * 2 + 0] = (float)i1;
        out[(size_t)TOKENS * 2 + (size_t)row * 2 + 1] = (float)i2;
    }
}

extern "C" void kernel_launch(void* const* d_in, const int* in_sizes, int n_in,
                              void* d_out, int out_size, void* d_ws, size_t ws_size,
                              hipStream_t stream) {
    const float* x = (const float*)d_in[0];
    const float* W = (const float*)d_in[1];
    float* out = (float*)d_out;
    router_kernel<<<TOKENS / BM, NT, 0, stream>>>(x, W, out);
}